// Round 3
// baseline (256.258 us; speedup 1.0000x reference)
//
#include <hip/hip_runtime.h>
#include <math.h>

// DivEncoder: x[N,H] -> per-group (D=512 groups, V=16) conv to U=64, ELU,
// conv U->1, row-wise L2 normalize. All fp32 in/out.
#define D_ 512
#define H_ 8192
#define U_ 64
#define V_ 16
#define N_ 4096

// Block geometry: 32 rows x 16 groups per block, 256 threads (4 waves).
// Wave w handles groups w*4..w*4+3 (all 2 row-tiles of 16 rows each).
#define BR 32            // rows per block
#define BG 16            // groups per block
#define XPAD 4           // LDS row padding (floats) -> stride 260, bank step 4
#define XSTR (BG * V_ + XPAD)   // 260

typedef __bf16 bf16x8 __attribute__((ext_vector_type(8)));
typedef float f32x4 __attribute__((ext_vector_type(4)));

// Split-precision bf16 MFMA (16x16x32): K=32 packs [hi | lo] of W1:
//   A = [w_hi (k0..15) | w_lo (k16..31)]
//   MFMA1 B=[x_hi|x_hi] -> w*x_hi ; MFMA2 B=[x_lo|x_lo] -> w*x_lo
//   sum = w*x (exact to ~2^-18 rel), fp32 accumulate, b1 preloaded in C.
// Fragment layouts (HW-verified): A/B: idx=lane&15, k=(lane>>4)*8+j ;
// C/D: col=lane&15, row=(lane>>4)*4+reg.
__global__ __launch_bounds__(256) void k1_div_encoder(
        const float* __restrict__ x,
        const float* __restrict__ W1,
        const float* __restrict__ b1,
        const float* __restrict__ W2,
        const float* __restrict__ b2,
        float* __restrict__ y) {
    __shared__ float xs[BR][XSTR];     // staged x tile (fp32)
    __shared__ float ytile[BR][BG + 1]; // y bounce tile (padded)

    const int tid  = threadIdx.x;
    const int lane = tid & 63;
    const int wave = __builtin_amdgcn_readfirstlane(tid >> 6);
    const int q    = lane >> 4;        // quad 0..3
    const int m    = lane & 15;
    const int vbase = (q & 1) * 8;     // which 8 v's this quad holds

    // nb fast so consecutive blocks share the same W1 slice (L2-resident).
    const int nb = blockIdx.x & 127;   // 128 row-blocks
    const int db = blockIdx.x >> 7;    // 32 group-blocks
    const int r0 = nb * BR;
    const int d0 = db * BG;

    // ---- stage 1: coalesced x -> LDS ----
    // Block region: rows r0..r0+31, cols d0*16 .. d0*16+255 (1 KB/row contig).
    {
        const float* xg = x + (size_t)r0 * H_ + (size_t)d0 * V_;
        #pragma unroll
        for (int i = 0; i < 8; ++i) {
            const int flat = tid + i * 256;   // 0..2047
            const int row  = flat >> 6;       // 0..31
            const int c4   = flat & 63;       // float4 column
            f32x4 v = *(const f32x4*)(xg + (size_t)row * H_ + c4 * 4);
            *(f32x4*)&xs[row][c4 * 4] = v;
        }
    }
    __syncthreads();

    // ---- stage 2: per-group MFMA + ELU + conv2 ----
    for (int gi = 0; gi < 4; ++gi) {
        const int gl = wave * 4 + gi;      // group local 0..15
        const int d  = d0 + gl;

        // A-frags: quads 0,1 hold w_hi; quads 2,3 hold w_lo (same v's).
        bf16x8 Afrag[4];
        #pragma unroll
        for (int c = 0; c < 4; ++c) {
            const float* wp = W1 + ((size_t)d * U_ + c * 16 + m) * V_ + vbase;
            f32x4 w0 = *(const f32x4*)wp;
            f32x4 w1v = *(const f32x4*)(wp + 4);
            float wf[8] = {w0.x, w0.y, w0.z, w0.w, w1v.x, w1v.y, w1v.z, w1v.w};
            bf16x8 a;
            if (q < 2) {
                #pragma unroll
                for (int i = 0; i < 8; ++i) a[i] = (__bf16)wf[i];
            } else {
                #pragma unroll
                for (int i = 0; i < 8; ++i) {
                    __bf16 h = (__bf16)wf[i];
                    a[i] = (__bf16)(wf[i] - (float)h);
                }
            }
            Afrag[c] = a;
        }
        // b1/W2 in C/D layout: u = c*16 + q*4 + r.
        f32x4 b1frag[4], w2frag[4];
        #pragma unroll
        for (int c = 0; c < 4; ++c) {
            b1frag[c] = *(const f32x4*)(b1 + (size_t)d * U_ + c * 16 + q * 4);
            w2frag[c] = *(const f32x4*)(W2 + (size_t)d * U_ + c * 16 + q * 4);
        }
        const float b2s = b2[d];

        #pragma unroll
        for (int t = 0; t < 2; ++t) {
            // B-frag from LDS: row = t*16+m, v = vbase+j.
            const float* bp = &xs[t * 16 + m][gl * V_ + vbase];
            f32x4 x0 = *(const f32x4*)bp;
            f32x4 x1 = *(const f32x4*)(bp + 4);
            float xf[8] = {x0.x, x0.y, x0.z, x0.w, x1.x, x1.y, x1.z, x1.w};
            bf16x8 bhi, blo;
            #pragma unroll
            for (int i = 0; i < 8; ++i) {
                __bf16 h = (__bf16)xf[i];
                bhi[i] = h;
                blo[i] = (__bf16)(xf[i] - (float)h);
            }

            float partial = 0.0f;
            #pragma unroll
            for (int c = 0; c < 4; ++c) {
                f32x4 acc = b1frag[c];
                acc = __builtin_amdgcn_mfma_f32_16x16x32_bf16(Afrag[c], bhi, acc, 0, 0, 0);
                acc = __builtin_amdgcn_mfma_f32_16x16x32_bf16(Afrag[c], blo, acc, 0, 0, 0);
                #pragma unroll
                for (int r = 0; r < 4; ++r) {
                    float h = acc[r];
                    float e = (h > 0.0f) ? h : (__expf(h) - 1.0f);  // elu
                    partial = fmaf(w2frag[c][r], e, partial);
                }
            }
            // lanes {m, m+16, m+32, m+48} hold disjoint u-subsets
            partial += __shfl_xor(partial, 16, 64);
            partial += __shfl_xor(partial, 32, 64);
            if (q == 0) {
                ytile[t * 16 + m][gl] = partial + b2s;
            }
        }
    }
    __syncthreads();

    // ---- stage 3: coalesced y store ----
    if (tid < 128) {
        const int row = tid >> 2;
        const int c4  = (tid & 3) * 4;
        f32x4 v;
        v.x = ytile[row][c4 + 0];
        v.y = ytile[row][c4 + 1];
        v.z = ytile[row][c4 + 2];
        v.w = ytile[row][c4 + 3];
        *(f32x4*)(y + (size_t)(r0 + row) * D_ + d0 + c4) = v;
    }
}

// Kernel 2: row-wise L2 normalize in place. One block (256 threads) per row.
__global__ __launch_bounds__(256) void k2_l2_normalize(float* __restrict__ y) {
    const int n = blockIdx.x;
    const int t = threadIdx.x;
    float* row = y + (size_t)n * D_;

    float v0 = row[t];
    float v1 = row[t + 256];
    float ss = v0 * v0 + v1 * v1;

    #pragma unroll
    for (int off = 32; off > 0; off >>= 1) {
        ss += __shfl_down(ss, off, 64);
    }

    __shared__ float wsum[4];
    if ((t & 63) == 0) wsum[t >> 6] = ss;
    __syncthreads();
    const float tot = wsum[0] + wsum[1] + wsum[2] + wsum[3];

    const float scale = 1.0f / fmaxf(sqrtf(tot), 1e-12f);

    row[t]       = v0 * scale;
    row[t + 256] = v1 * scale;
}

extern "C" void kernel_launch(void* const* d_in, const int* in_sizes, int n_in,
                              void* d_out, int out_size, void* d_ws, size_t ws_size,
                              hipStream_t stream) {
    const float* x  = (const float*)d_in[0];
    const float* W1 = (const float*)d_in[1];
    const float* b1 = (const float*)d_in[2];
    const float* W2 = (const float*)d_in[3];
    const float* b2 = (const float*)d_in[4];
    float* y = (float*)d_out;  // [N, D] fp32

    k1_div_encoder<<<dim3((N_ / BR) * (D_ / BG)), dim3(256), 0, stream>>>(
        x, W1, b1, W2, b2, y);
    k2_l2_normalize<<<dim3(N_), dim3(256), 0, stream>>>(y);
}

// Round 4
// 220.606 us; speedup vs baseline: 1.1616x; 1.1616x over previous
//
#include <hip/hip_runtime.h>
#include <math.h>

// DivEncoder: x[N,H] -> per-group (D=512 groups, V=16) conv to U=64, ELU,
// conv U->1, row-wise L2 normalize. All fp32 in/out.
#define D_ 512
#define H_ 8192
#define U_ 64
#define V_ 16
#define N_ 4096
#define DUV (D_ * U_ * V_)     // 524288

// Block geometry: 64 rows x 8 groups, 256 threads (4 waves).
// Wave w handles groups {2w, 2w+1}, all 4 row-tiles of 16 rows each.
#define BR 64
#define BG 8
#define XSTR (BG * V_ + 4)     // 132 floats: pad 4 -> 16B-aligned rows, bank rot 4
#define YSTR 12                // 8 used + pad -> 16B-aligned f32x4 reads

typedef __bf16 bf16x8 __attribute__((ext_vector_type(8)));
typedef __bf16 bf16x4 __attribute__((ext_vector_type(4)));
typedef float f32x4 __attribute__((ext_vector_type(4)));

// Prep: split W1 fp32 -> hi/lo bf16 (same [d][u][v] layout), once per launch.
// wh = ws, wl = ws + DUV. 2 MB total, ~1 us.
__global__ __launch_bounds__(256) void k0_split_w1(const float* __restrict__ W1,
                                                   __bf16* __restrict__ wh) {
    __bf16* wl = wh + DUV;
    const int i4 = (blockIdx.x * 256 + threadIdx.x) * 4;
    f32x4 w = *(const f32x4*)(W1 + i4);
    bf16x4 h, l;
    #pragma unroll
    for (int j = 0; j < 4; ++j) {
        float wf = w[j];
        __bf16 hh = (__bf16)wf;
        h[j] = hh;
        l[j] = (__bf16)(wf - (float)hh);
    }
    *(bf16x4*)(wh + i4) = h;
    *(bf16x4*)(wl + i4) = l;
}

// Split-precision bf16 MFMA (16x16x32): K packs [w_hi | w_lo]:
//   MFMA1 B=[x_hi|x_hi] -> w*x_hi ; MFMA2 B=[x_lo|x_lo] -> w*x_lo
// sum = w*x exact to ~2^-16 rel, fp32 accum, b1 preloaded in C.
// Layouts (HW-verified): A/B: idx=lane&15, k=(lane>>4)*8+j ;
// C/D: col=lane&15, row=(lane>>4)*4+reg.
template <bool PRESPLIT>
__global__ __launch_bounds__(256, 4) void k1_div_encoder(
        const float* __restrict__ x,
        const float* __restrict__ W1,
        const __bf16* __restrict__ wsplit,
        const float* __restrict__ b1,
        const float* __restrict__ W2,
        const float* __restrict__ b2,
        float* __restrict__ y) {
    __shared__ float xs[BR][XSTR];
    __shared__ float ytile[BR][YSTR];

    const int tid  = threadIdx.x;
    const int lane = tid & 63;
    const int wave = __builtin_amdgcn_readfirstlane(tid >> 6);
    const int q    = lane >> 4;
    const int m    = lane & 15;
    const int vbase = (q & 1) * 8;

    // nb fast: 64 consecutive blocks reuse the same 16 KB weight slice (L2).
    const int nb = blockIdx.x & 63;    // 64 row-blocks
    const int db = blockIdx.x >> 6;    // 64 group-blocks
    const int r0 = nb * BR;
    const int d0 = db * BG;

    // ---- stage x -> LDS (coalesced, 512 B contiguous per row) ----
    {
        const float* xg = x + (size_t)r0 * H_ + (size_t)d0 * V_;
        #pragma unroll
        for (int i = 0; i < 8; ++i) {
            const int flat = tid + i * 256;   // 0..2047
            const int row  = flat >> 5;       // 0..63
            const int c4   = flat & 31;       // f32x4 col
            f32x4 v = *(const f32x4*)(xg + (size_t)row * H_ + c4 * 4);
            *(f32x4*)&xs[row][c4 * 4] = v;
        }
    }
    __syncthreads();

    #pragma unroll 1   // keep regs low: one group's frags live at a time
    for (int gi = 0; gi < 2; ++gi) {
        const int gl = wave * 2 + gi;
        const int d  = d0 + gl;

        // A-frags: quads 0,1 = w_hi, quads 2,3 = w_lo (same v's).
        bf16x8 Afrag[4];
        if (PRESPLIT) {
            const __bf16* base = wsplit + (size_t)(q >> 1) * DUV;
            #pragma unroll
            for (int c = 0; c < 4; ++c) {
                Afrag[c] = *(const bf16x8*)(base +
                    ((size_t)d * U_ + c * 16 + m) * V_ + vbase);
            }
        } else {
            #pragma unroll
            for (int c = 0; c < 4; ++c) {
                const float* wp = W1 + ((size_t)d * U_ + c * 16 + m) * V_ + vbase;
                f32x4 w0 = *(const f32x4*)wp;
                f32x4 w1v = *(const f32x4*)(wp + 4);
                float wf[8] = {w0.x, w0.y, w0.z, w0.w, w1v.x, w1v.y, w1v.z, w1v.w};
                bf16x8 a;
                #pragma unroll
                for (int i = 0; i < 8; ++i) {
                    __bf16 h = (__bf16)wf[i];
                    __bf16 l = (__bf16)(wf[i] - (float)h);
                    a[i] = (q < 2) ? h : l;   // cndmask, branchless
                }
                Afrag[c] = a;
            }
        }

        // b1/W2 in C/D layout: u = c*16 + q*4 + r.
        f32x4 b1frag[4], w2frag[4];
        #pragma unroll
        for (int c = 0; c < 4; ++c) {
            b1frag[c] = *(const f32x4*)(b1 + (size_t)d * U_ + c * 16 + q * 4);
            w2frag[c] = *(const f32x4*)(W2 + (size_t)d * U_ + c * 16 + q * 4);
        }
        const float b2s = b2[d];

        #pragma unroll 2
        for (int t = 0; t < 4; ++t) {
            const float* bp = &xs[t * 16 + m][gl * V_ + vbase];
            f32x4 x0 = *(const f32x4*)bp;
            f32x4 x1 = *(const f32x4*)(bp + 4);
            float xf[8] = {x0.x, x0.y, x0.z, x0.w, x1.x, x1.y, x1.z, x1.w};
            bf16x8 bhi, blo;
            #pragma unroll
            for (int i = 0; i < 8; ++i) {
                __bf16 h = (__bf16)xf[i];
                bhi[i] = h;
                blo[i] = (__bf16)(xf[i] - (float)h);
            }

            float partial = 0.0f;
            #pragma unroll
            for (int c = 0; c < 4; ++c) {
                f32x4 acc = b1frag[c];
                acc = __builtin_amdgcn_mfma_f32_16x16x32_bf16(Afrag[c], bhi, acc, 0, 0, 0);
                acc = __builtin_amdgcn_mfma_f32_16x16x32_bf16(Afrag[c], blo, acc, 0, 0, 0);
                #pragma unroll
                for (int r = 0; r < 4; ++r) {
                    float h = acc[r];
                    // branchless ELU: max(h, expm1(min(h,0)))
                    float e = fmaxf(h, __expf(fminf(h, 0.0f)) - 1.0f);
                    partial = fmaf(w2frag[c][r], e, partial);
                }
            }
            partial += __shfl_xor(partial, 16, 64);
            partial += __shfl_xor(partial, 32, 64);
            if (q == 0) {
                ytile[t * 16 + m][gl] = partial + b2s;
            }
        }
    }
    __syncthreads();

    // ---- coalesced y store ----
    if (tid < 128) {
        const int row  = tid >> 1;
        const int half = tid & 1;
        f32x4 v = *(const f32x4*)&ytile[row][half * 4];
        *(f32x4*)(y + (size_t)(r0 + row) * D_ + d0 + half * 4) = v;
    }
}

// Kernel 2: row-wise L2 normalize in place. One block (256 threads) per row.
__global__ __launch_bounds__(256) void k2_l2_normalize(float* __restrict__ y) {
    const int n = blockIdx.x;
    const int t = threadIdx.x;
    float* row = y + (size_t)n * D_;

    float v0 = row[t];
    float v1 = row[t + 256];
    float ss = v0 * v0 + v1 * v1;

    #pragma unroll
    for (int off = 32; off > 0; off >>= 1) {
        ss += __shfl_down(ss, off, 64);
    }

    __shared__ float wsum[4];
    if ((t & 63) == 0) wsum[t >> 6] = ss;
    __syncthreads();
    const float tot = wsum[0] + wsum[1] + wsum[2] + wsum[3];

    const float scale = 1.0f / fmaxf(sqrtf(tot), 1e-12f);

    row[t]       = v0 * scale;
    row[t + 256] = v1 * scale;
}

extern "C" void kernel_launch(void* const* d_in, const int* in_sizes, int n_in,
                              void* d_out, int out_size, void* d_ws, size_t ws_size,
                              hipStream_t stream) {
    const float* x  = (const float*)d_in[0];
    const float* W1 = (const float*)d_in[1];
    const float* b1 = (const float*)d_in[2];
    const float* W2 = (const float*)d_in[3];
    const float* b2 = (const float*)d_in[4];
    float* y = (float*)d_out;  // [N, D] fp32

    const dim3 grid((N_ / BR) * (D_ / BG));
    if (ws_size >= (size_t)(2 * DUV * sizeof(__bf16))) {
        __bf16* wh = (__bf16*)d_ws;
        k0_split_w1<<<dim3(DUV / 4 / 256), dim3(256), 0, stream>>>(W1, wh);
        k1_div_encoder<true><<<grid, dim3(256), 0, stream>>>(
            x, W1, wh, b1, W2, b2, y);
    } else {
        k1_div_encoder<false><<<grid, dim3(256), 0, stream>>>(
            x, W1, (const __bf16*)nullptr, b1, W2, b2, y);
    }
    k2_l2_normalize<<<dim3(N_), dim3(256), 0, stream>>>(y);
}